// Round 2
// baseline (1385.777 us; speedup 1.0000x reference)
//
#include <hip/hip_runtime.h>
#include <hip/hip_bf16.h>

typedef __attribute__((ext_vector_type(8))) short s16x8;
typedef __attribute__((ext_vector_type(4))) short s16x4;
typedef __attribute__((ext_vector_type(4))) float f32x4;

#define MFMA(a, b, c) __builtin_amdgcn_mfma_f32_16x16x32_bf16((a), (b), (c), 0, 0, 0)

#if __has_builtin(__builtin_amdgcn_mfma_f32_16x16x16bf16_1k)
#define MFMA16(a, b, c) __builtin_amdgcn_mfma_f32_16x16x16bf16_1k((a), (b), (c), 0, 0, 0)
#else
__device__ __forceinline__ f32x4 mfma16_asm(s16x4 a, s16x4 b, f32x4 c) {
  asm volatile("v_mfma_f32_16x16x16_bf16 %0, %1, %2, %0\n\ts_nop 7\n\ts_nop 7"
               : "+v"(c) : "v"(a), "v"(b));
  return c;
}
#define MFMA16(a, b, c) mfma16_asm((a), (b), (c))
#endif

__device__ __forceinline__ short f2bf(float f) {
  unsigned u = __builtin_bit_cast(unsigned, f);
  u += 0x7FFFu + ((u >> 16) & 1u);
  return (short)(u >> 16);
}
__device__ __forceinline__ float bf2f(short s) {
  unsigned u = ((unsigned)(unsigned short)s) << 16;
  return __builtin_bit_cast(float, u);
}
__device__ __forceinline__ void async16(const void* g, void* l) {
  __builtin_amdgcn_global_load_lds((const __attribute__((address_space(1))) void*)g,
                                   (__attribute__((address_space(3))) void*)l, 16, 0, 0);
}

// ---------------- convert / transpose helpers ----------------

__global__ __launch_bounds__(256) void f32_to_bf16_k(const float* __restrict__ in,
                                                     short* __restrict__ out, int n4) {
  int i = blockIdx.x * 256 + threadIdx.x;
  if (i >= n4) return;
  float4 v = ((const float4*)in)[i];
  short4 o;
  o.x = f2bf(v.x); o.y = f2bf(v.y); o.z = f2bf(v.z); o.w = f2bf(v.w);
  ((short4*)out)[i] = o;
}

// out[n*K + k] = bf16(in[k*N + n]);  (B^T layout for GEMM)
__global__ __launch_bounds__(256) void transpose_bf16_k(const float* __restrict__ in,
                                                        short* __restrict__ out, int K, int N) {
  int idx = blockIdx.x * 256 + threadIdx.x;
  if (idx >= K * N) return;
  int n = idx / K;
  int k = idx - n * K;
  out[idx] = f2bf(in[k * N + n]);
}

// ---------------- GEMM core: 128x128 tile, BK=64, bf16 MFMA ----------------

__device__ __forceinline__ void gemm_core(const short* __restrict__ A, const short* __restrict__ Bt,
                                          short* Asm, short* Bsm, int m0, int n0,
                                          f32x4 (&acc)[4][4]) {
  const int tid = threadIdx.x;
  const int lane = tid & 63;
  const int w = tid >> 6;
  const int wm = w >> 1, wn = w & 1;
  const int l15 = lane & 15, qd = lane >> 4;

  for (int kt = 0; kt < 12; ++kt) {
    __syncthreads();
#pragma unroll
    for (int i = 0; i < 4; ++i) {
      int s = i * 256 + tid;
      int row = s >> 3, cst = s & 7;
      int cg = cst ^ (row & 7);
      async16(A + (m0 + row) * 768 + kt * 64 + cg * 8, Asm + s * 8);
      async16(Bt + (n0 + row) * 768 + kt * 64 + cg * 8, Bsm + s * 8);
    }
    __builtin_amdgcn_s_waitcnt(0x0f70);  // vmcnt(0)
    __syncthreads();
#pragma unroll
    for (int ks = 0; ks < 2; ++ks) {
      s16x8 af[4], bfr[4];
#pragma unroll
      for (int mt = 0; mt < 4; ++mt) {
        int row = wm * 64 + mt * 16 + l15;
        int kc = ks * 4 + qd;
        af[mt] = *(const s16x8*)(Asm + row * 64 + ((kc ^ (row & 7)) << 3));
      }
#pragma unroll
      for (int nt = 0; nt < 4; ++nt) {
        int row = wn * 64 + nt * 16 + l15;
        int kc = ks * 4 + qd;
        bfr[nt] = *(const s16x8*)(Bsm + row * 64 + ((kc ^ (row & 7)) << 3));
      }
#pragma unroll
      for (int mt = 0; mt < 4; ++mt)
#pragma unroll
        for (int nt = 0; nt < 4; ++nt)
          acc[mt][nt] = MFMA(af[mt], bfr[nt], acc[mt][nt]);
    }
  }
}

// GEMM1: qkv = x_bf @ Wqkv + b.  Scatter epilogue to q/k/v (B,H,197,64) bf16.
__global__ __launch_bounds__(256) void gemm_qkv(const short* __restrict__ A, const short* __restrict__ Bt,
                                                const float* __restrict__ bias,
                                                short* __restrict__ qo, short* __restrict__ ko,
                                                short* __restrict__ vo) {
  __shared__ short Asm[128 * 64];
  __shared__ short Bsm[128 * 64];
  const int m0 = blockIdx.y * 128;  // n-fastest grid for A-tile L2 reuse
  const int n0 = blockIdx.x * 128;
  const f32x4 z4 = {0.f, 0.f, 0.f, 0.f};
  f32x4 acc[4][4];
#pragma unroll
  for (int i = 0; i < 4; ++i)
#pragma unroll
    for (int j = 0; j < 4; ++j) acc[i][j] = z4;
  gemm_core(A, Bt, Asm, Bsm, m0, n0, acc);

  const int tid = threadIdx.x, lane = tid & 63, w = tid >> 6;
  const int wm = w >> 1, wn = w & 1, l15 = lane & 15, qd = lane >> 4;

  float bv[4];
  short* dstp[4];
  int coff[4];
#pragma unroll
  for (int nt = 0; nt < 4; ++nt) {
    int n = n0 + wn * 64 + nt * 16 + l15;
    bv[nt] = bias[n];
    int s = n / 768;
    int rem = n - s * 768;
    int hh = rem >> 6, d = rem & 63;
    dstp[nt] = (s == 0) ? qo : ((s == 1) ? ko : vo);
    coff[nt] = hh * 197 * 64 + d;
  }
#pragma unroll
  for (int mt = 0; mt < 4; ++mt) {
#pragma unroll
    for (int r = 0; r < 4; ++r) {
      int m = m0 + wm * 64 + mt * 16 + qd * 4 + r;
      int bb = m / 197;
      int tok = m - bb * 197;
      size_t base = (size_t)bb * (12 * 197 * 64) + (size_t)tok * 64;
#pragma unroll
      for (int nt = 0; nt < 4; ++nt)
        dstp[nt][base + coff[nt]] = f2bf(acc[mt][nt][r] + bv[nt]);
    }
  }
}

// GEMM2: out = aout_bf @ Wproj + b, fp32 row-major output.
__global__ __launch_bounds__(256) void gemm_proj(const short* __restrict__ A, const short* __restrict__ Bt,
                                                 const float* __restrict__ bias,
                                                 float* __restrict__ out) {
  __shared__ short Asm[128 * 64];
  __shared__ short Bsm[128 * 64];
  const int m0 = blockIdx.y * 128;
  const int n0 = blockIdx.x * 128;
  const f32x4 z4 = {0.f, 0.f, 0.f, 0.f};
  f32x4 acc[4][4];
#pragma unroll
  for (int i = 0; i < 4; ++i)
#pragma unroll
    for (int j = 0; j < 4; ++j) acc[i][j] = z4;
  gemm_core(A, Bt, Asm, Bsm, m0, n0, acc);

  const int tid = threadIdx.x, lane = tid & 63, w = tid >> 6;
  const int wm = w >> 1, wn = w & 1, l15 = lane & 15, qd = lane >> 4;
#pragma unroll
  for (int mt = 0; mt < 4; ++mt) {
#pragma unroll
    for (int r = 0; r < 4; ++r) {
      int m = m0 + wm * 64 + mt * 16 + qd * 4 + r;
      float* orow = out + (size_t)m * 768;
#pragma unroll
      for (int nt = 0; nt < 4; ++nt) {
        int n = n0 + wn * 64 + nt * 16 + l15;
        orow[n] = acc[mt][nt][r] + bias[n];
      }
    }
  }
}

// ---------------- fused attention (S^T formulation) + depthwise conv ----------------
// 1 WG = (b,h), 512 threads (8 waves). K in LDS [197][64] swizzled chunks;
// V^T in LDS [64][256] swizzled (keys 197..207 zeroed). S computed transposed:
// MFMA(A=K, B=Q) -> lane holds S^T[key=kt*16+qd*4+r][tok=l15], which IS the
// A-operand layout of mfma_16x16x16 for PV — no LDS round-trip for P.
// Conv phase after barrier: fixed-d threads, weights in regs, global RMW on aout.
__global__ __launch_bounds__(512, 4) void attn_fused(const short* __restrict__ qa, const short* __restrict__ ka,
                                                     const short* __restrict__ va,
                                                     const float* __restrict__ dwcw,
                                                     const float* __restrict__ dwcb,
                                                     short* __restrict__ aout) {
  __shared__ short Klds[197 * 64];   // 25.2 KB
  __shared__ short Vt[64 * 256];     // 32.8 KB  (total 58 KB -> 2 blocks/CU)

  const int tid = threadIdx.x;
  const int lane = tid & 63;
  const int w = tid >> 6;            // 0..7
  const int l15 = lane & 15, qd = lane >> 4;
  const int bh = blockIdx.x;
  const int b = bh / 12;
  const int h = bh - b * 12;
  const short* kb = ka + (size_t)bh * (197 * 64);
  const short* vb = va + (size_t)bh * (197 * 64);
  const short* qb = qa + (size_t)bh * (197 * 64);

  // stage K: linear LDS slots, swizzle applied to the GLOBAL chunk index
  for (int s = tid; s < 197 * 8; s += 512) {
    int row = s >> 3, cst = s & 7;
    int cg = cst ^ (row & 7);
    async16(kb + row * 64 + cg * 8, Klds + s * 8);
  }
  // stage V transposed: coalesced global u16 reads (lane-consecutive d = one
  // 128B row per instr), swizzled b64 LDS writes. keys >=197 -> 0.
  for (int t = tid; t < 64 * 52; t += 512) {
    int d = t & 63, kc4 = t >> 6;   // kc4: 4-key chunk, keys kc4*4..+3 (0..207)
    s16x4 pack;
#pragma unroll
    for (int j = 0; j < 4; ++j) {
      int key = kc4 * 4 + j;
      pack[j] = (key <= 196) ? vb[key * 64 + d] : (short)0;
    }
    int kc8 = kc4 >> 1, sub = (kc4 & 1) * 4;
    *(s16x4*)(Vt + d * 256 + ((kc8 ^ (d & 7)) << 3) + sub) = pack;
  }
  __builtin_amdgcn_s_waitcnt(0x0f70);  // vmcnt(0) for async16
  __syncthreads();

  const float scale_log2e = 0.125f * 1.44269504f;
  const f32x4 z4 = {0.f, 0.f, 0.f, 0.f};

  for (int qt = w; qt < 13; qt += 8) {
    const int m0 = qt * 16;
    int mrow = m0 + l15; if (mrow > 196) mrow = 196;
    s16x8 qf0 = *(const s16x8*)(qb + mrow * 64 + qd * 8);
    s16x8 qf1 = *(const s16x8*)(qb + mrow * 64 + 32 + qd * 8);

    // S^T = K Q^T: lane (qd,l15) holds keys kt*16+qd*4+r for tok=m0+l15
    f32x4 S[13];
#pragma unroll
    for (int kt = 0; kt < 13; ++kt) {
      int krow = kt * 16 + l15; if (krow > 196) krow = 196;
      s16x8 kf0 = *(const s16x8*)(Klds + krow * 64 + ((qd ^ (krow & 7)) << 3));
      s16x8 kf1 = *(const s16x8*)(Klds + krow * 64 + (((4 + qd) ^ (krow & 7)) << 3));
      f32x4 sa = z4;
      sa = MFMA(kf0, qf0, sa);
      sa = MFMA(kf1, qf1, sa);
      S[kt] = sa;
    }
    // mask invalid keys in tile 12 (key = 192 + qd*4 + r valid iff qd*4+r <= 4)
#pragma unroll
    for (int r = 0; r < 4; ++r)
      if (qd * 4 + r > 4) S[12][r] = -3.0e38f;

    // softmax over keys for tok=l15: in-lane (52 vals) + reduce across qd
    float mx = -3.0e38f;
#pragma unroll
    for (int kt = 0; kt < 13; ++kt)
#pragma unroll
      for (int r = 0; r < 4; ++r) mx = fmaxf(mx, S[kt][r]);
    mx = fmaxf(mx, __shfl_xor(mx, 16));
    mx = fmaxf(mx, __shfl_xor(mx, 32));

    float l = 0.f;
#pragma unroll
    for (int kt = 0; kt < 13; ++kt) {
#pragma unroll
      for (int r = 0; r < 4; ++r) {
        float p = __builtin_amdgcn_exp2f((S[kt][r] - mx) * scale_log2e);
        S[kt][r] = p;
        l += p;
      }
    }
    l += __shfl_xor(l, 16);
    l += __shfl_xor(l, 32);
    float linv = __builtin_amdgcn_rcpf(l);

    // O = P V via 16x16x16 MFMA: A-frag (P) is the lane's OWN S values
    f32x4 O[4] = {z4, z4, z4, z4};
#pragma unroll
    for (int kt = 0; kt < 13; ++kt) {
      s16x4 a4;
#pragma unroll
      for (int r = 0; r < 4; ++r) a4[r] = f2bf(S[kt][r] * linv);
      int kc8b = kt * 2 + (qd >> 1);
      int sub = (qd & 1) * 4;
#pragma unroll
      for (int nt = 0; nt < 4; ++nt) {
        int d = nt * 16 + l15;
        s16x4 vf = *(const s16x4*)(Vt + d * 256 + ((kc8b ^ (d & 7)) << 3) + sub);
        O[nt] = MFMA16(a4, vf, O[nt]);
      }
    }

    // store: C-layout (tok = m0+qd*4+r, d = nt*16+l15)
#pragma unroll
    for (int r = 0; r < 4; ++r) {
      int tok = m0 + qd * 4 + r;
      if (tok > 196) continue;
      size_t ob = ((size_t)b * 197 + tok) * 768 + h * 64;
#pragma unroll
      for (int nt = 0; nt < 4; ++nt)
        aout[ob + nt * 16 + l15] = f2bf(O[nt][r]);
    }
  }

  __syncthreads();  // all O stores of this block drained (vmcnt(0) + barrier)

  // depthwise 3x3 conv on V, added into this block's aout slice.
  // thread owns fixed channel d; weights in registers; reads/writes coalesced
  // (lane-consecutive d -> 128B lines), V is L2-hot from staging.
  {
    const int d = tid & 63;
    const int seg = tid >> 6;
    float wreg[9];
#pragma unroll
    for (int tp = 0; tp < 9; ++tp) wreg[tp] = dwcw[(h * 64 + d) * 9 + tp];
    const float breg = dwcb[h * 64 + d];

    for (int c = seg; c < 28; c += 8) {   // (y, x-half) chunks: 14 rows x 2
      int y = c >> 1;
      int xb = (c & 1) * 8;
      int xn = (c & 1) ? 6 : 8;
      float vv[3][10];
#pragma unroll
      for (int dy = 0; dy < 3; ++dy) {
        int yy = y - 1 + dy;
#pragma unroll
        for (int k = 0; k < 10; ++k) {
          int xx = xb - 1 + k;
          float val = 0.f;
          if (yy >= 0 && yy < 14 && xx >= 0 && xx < 14) {
            int key = 1 + yy * 14 + xx;
            val = bf2f(vb[key * 64 + d]);
          }
          vv[dy][k] = val;
        }
      }
#pragma unroll
      for (int x = 0; x < 8; ++x) {
        if (x >= xn) break;
        float acc = breg;
#pragma unroll
        for (int dy = 0; dy < 3; ++dy)
#pragma unroll
          for (int dx = 0; dx < 3; ++dx)
            acc += wreg[dy * 3 + dx] * vv[dy][x + dx];
        int tok = 1 + y * 14 + xb + x;
        size_t oa = ((size_t)b * 197 + tok) * 768 + h * 64 + d;
        aout[oa] = f2bf(bf2f(aout[oa]) + acc);
      }
    }
  }
}

// ---------------- launch ----------------

extern "C" void kernel_launch(void* const* d_in, const int* in_sizes, int n_in,
                              void* d_out, int out_size, void* d_ws, size_t ws_size,
                              hipStream_t stream) {
  const float* x     = (const float*)d_in[0];
  const float* Wqkv  = (const float*)d_in[1];
  const float* bqkv  = (const float*)d_in[2];
  const float* Wproj = (const float*)d_in[3];
  const float* bproj = (const float*)d_in[4];
  const float* dwcw  = (const float*)d_in[5];
  const float* dwcb  = (const float*)d_in[6];
  float* out = (float*)d_out;

  const size_t XE = (size_t)50432 * 768;
  short* ws     = (short*)d_ws;
  short* xbf    = ws;
  short* wqkvT  = xbf + XE;
  short* wprojT = wqkvT + (size_t)2304 * 768;
  short* qarr   = wprojT + (size_t)768 * 768;
  short* karr   = qarr + XE;
  short* varr   = karr + XE;
  short* aoutb  = xbf;  // reuse x_bf space (dead after gemm_qkv)

  f32_to_bf16_k<<<(int)((XE / 4 + 255) / 256), 256, 0, stream>>>(x, xbf, (int)(XE / 4));
  transpose_bf16_k<<<(2304 * 768 + 255) / 256, 256, 0, stream>>>(Wqkv, wqkvT, 768, 2304);
  transpose_bf16_k<<<(768 * 768 + 255) / 256, 256, 0, stream>>>(Wproj, wprojT, 768, 768);
  gemm_qkv<<<dim3(18, 394), 256, 0, stream>>>(xbf, wqkvT, bqkv, qarr, karr, varr);
  attn_fused<<<3072, 512, 0, stream>>>(qarr, karr, varr, dwcw, dwcb, aoutb);
  gemm_proj<<<dim3(6, 394), 256, 0, stream>>>(aoutb, wprojT, bproj, out);
}

// Round 3
// 1294.150 us; speedup vs baseline: 1.0708x; 1.0708x over previous
//
#include <hip/hip_runtime.h>
#include <hip/hip_bf16.h>

typedef __attribute__((ext_vector_type(8))) short s16x8;
typedef __attribute__((ext_vector_type(4))) short s16x4;
typedef __attribute__((ext_vector_type(4))) float f32x4;

#define MFMA(a, b, c) __builtin_amdgcn_mfma_f32_16x16x32_bf16((a), (b), (c), 0, 0, 0)

#if __has_builtin(__builtin_amdgcn_mfma_f32_16x16x16bf16_1k)
#define MFMA16(a, b, c) __builtin_amdgcn_mfma_f32_16x16x16bf16_1k((a), (b), (c), 0, 0, 0)
#else
__device__ __forceinline__ f32x4 mfma16_asm(s16x4 a, s16x4 b, f32x4 c) {
  asm volatile("v_mfma_f32_16x16x16_bf16 %0, %1, %2, %0\n\ts_nop 7\n\ts_nop 7"
               : "+v"(c) : "v"(a), "v"(b));
  return c;
}
#define MFMA16(a, b, c) mfma16_asm((a), (b), (c))
#endif

__device__ __forceinline__ short f2bf(float f) {
  unsigned u = __builtin_bit_cast(unsigned, f);
  u += 0x7FFFu + ((u >> 16) & 1u);
  return (short)(u >> 16);
}
__device__ __forceinline__ float bf2f(short s) {
  unsigned u = ((unsigned)(unsigned short)s) << 16;
  return __builtin_bit_cast(float, u);
}
__device__ __forceinline__ void async16(const void* g, void* l) {
  __builtin_amdgcn_global_load_lds((const __attribute__((address_space(1))) void*)g,
                                   (__attribute__((address_space(3))) void*)l, 16, 0, 0);
}

// ---------------- convert / transpose helpers ----------------

__global__ __launch_bounds__(256) void f32_to_bf16_k(const float* __restrict__ in,
                                                     short* __restrict__ out, int n4) {
  int i = blockIdx.x * 256 + threadIdx.x;
  if (i >= n4) return;
  float4 v = ((const float4*)in)[i];
  short4 o;
  o.x = f2bf(v.x); o.y = f2bf(v.y); o.z = f2bf(v.z); o.w = f2bf(v.w);
  ((short4*)out)[i] = o;
}

// out[n*K + k] = bf16(in[k*N + n]);  (B^T layout for GEMM)
__global__ __launch_bounds__(256) void transpose_bf16_k(const float* __restrict__ in,
                                                        short* __restrict__ out, int K, int N) {
  int idx = blockIdx.x * 256 + threadIdx.x;
  if (idx >= K * N) return;
  int n = idx / K;
  int k = idx - n * K;
  out[idx] = f2bf(in[k * N + n]);
}

// ---------------- GEMM core: 128x128 tile, BK=64, bf16 MFMA ----------------

__device__ __forceinline__ void gemm_core(const short* __restrict__ A, const short* __restrict__ Bt,
                                          short* Asm, short* Bsm, int m0, int n0,
                                          f32x4 (&acc)[4][4]) {
  const int tid = threadIdx.x;
  const int lane = tid & 63;
  const int w = tid >> 6;
  const int wm = w >> 1, wn = w & 1;
  const int l15 = lane & 15, qd = lane >> 4;

  for (int kt = 0; kt < 12; ++kt) {
    __syncthreads();
#pragma unroll
    for (int i = 0; i < 4; ++i) {
      int s = i * 256 + tid;
      int row = s >> 3, cst = s & 7;
      int cg = cst ^ (row & 7);
      async16(A + (m0 + row) * 768 + kt * 64 + cg * 8, Asm + s * 8);
      async16(Bt + (n0 + row) * 768 + kt * 64 + cg * 8, Bsm + s * 8);
    }
    __builtin_amdgcn_s_waitcnt(0x0f70);  // vmcnt(0)
    __syncthreads();
#pragma unroll
    for (int ks = 0; ks < 2; ++ks) {
      s16x8 af[4], bfr[4];
#pragma unroll
      for (int mt = 0; mt < 4; ++mt) {
        int row = wm * 64 + mt * 16 + l15;
        int kc = ks * 4 + qd;
        af[mt] = *(const s16x8*)(Asm + row * 64 + ((kc ^ (row & 7)) << 3));
      }
#pragma unroll
      for (int nt = 0; nt < 4; ++nt) {
        int row = wn * 64 + nt * 16 + l15;
        int kc = ks * 4 + qd;
        bfr[nt] = *(const s16x8*)(Bsm + row * 64 + ((kc ^ (row & 7)) << 3));
      }
#pragma unroll
      for (int mt = 0; mt < 4; ++mt)
#pragma unroll
        for (int nt = 0; nt < 4; ++nt)
          acc[mt][nt] = MFMA(af[mt], bfr[nt], acc[mt][nt]);
    }
  }
}

// GEMM1: qkv = x_bf @ Wqkv + b.  Scatter epilogue to q/k/v (B,H,197,64) bf16.
__global__ __launch_bounds__(256) void gemm_qkv(const short* __restrict__ A, const short* __restrict__ Bt,
                                                const float* __restrict__ bias,
                                                short* __restrict__ qo, short* __restrict__ ko,
                                                short* __restrict__ vo) {
  __shared__ short Asm[128 * 64];
  __shared__ short Bsm[128 * 64];
  const int m0 = blockIdx.y * 128;  // n-fastest grid for A-tile L2 reuse
  const int n0 = blockIdx.x * 128;
  const f32x4 z4 = {0.f, 0.f, 0.f, 0.f};
  f32x4 acc[4][4];
#pragma unroll
  for (int i = 0; i < 4; ++i)
#pragma unroll
    for (int j = 0; j < 4; ++j) acc[i][j] = z4;
  gemm_core(A, Bt, Asm, Bsm, m0, n0, acc);

  const int tid = threadIdx.x, lane = tid & 63, w = tid >> 6;
  const int wm = w >> 1, wn = w & 1, l15 = lane & 15, qd = lane >> 4;

  float bv[4];
  short* dstp[4];
  int coff[4];
#pragma unroll
  for (int nt = 0; nt < 4; ++nt) {
    int n = n0 + wn * 64 + nt * 16 + l15;
    bv[nt] = bias[n];
    int s = n / 768;
    int rem = n - s * 768;
    int hh = rem >> 6, d = rem & 63;
    dstp[nt] = (s == 0) ? qo : ((s == 1) ? ko : vo);
    coff[nt] = hh * 197 * 64 + d;
  }
#pragma unroll
  for (int mt = 0; mt < 4; ++mt) {
#pragma unroll
    for (int r = 0; r < 4; ++r) {
      int m = m0 + wm * 64 + mt * 16 + qd * 4 + r;
      int bb = m / 197;
      int tok = m - bb * 197;
      size_t base = (size_t)bb * (12 * 197 * 64) + (size_t)tok * 64;
#pragma unroll
      for (int nt = 0; nt < 4; ++nt)
        dstp[nt][base + coff[nt]] = f2bf(acc[mt][nt][r] + bv[nt]);
    }
  }
}

// GEMM2: out = aout_bf @ Wproj + b, fp32 row-major output.
__global__ __launch_bounds__(256) void gemm_proj(const short* __restrict__ A, const short* __restrict__ Bt,
                                                 const float* __restrict__ bias,
                                                 float* __restrict__ out) {
  __shared__ short Asm[128 * 64];
  __shared__ short Bsm[128 * 64];
  const int m0 = blockIdx.y * 128;
  const int n0 = blockIdx.x * 128;
  const f32x4 z4 = {0.f, 0.f, 0.f, 0.f};
  f32x4 acc[4][4];
#pragma unroll
  for (int i = 0; i < 4; ++i)
#pragma unroll
    for (int j = 0; j < 4; ++j) acc[i][j] = z4;
  gemm_core(A, Bt, Asm, Bsm, m0, n0, acc);

  const int tid = threadIdx.x, lane = tid & 63, w = tid >> 6;
  const int wm = w >> 1, wn = w & 1, l15 = lane & 15, qd = lane >> 4;
#pragma unroll
  for (int mt = 0; mt < 4; ++mt) {
#pragma unroll
    for (int r = 0; r < 4; ++r) {
      int m = m0 + wm * 64 + mt * 16 + qd * 4 + r;
      float* orow = out + (size_t)m * 768;
#pragma unroll
      for (int nt = 0; nt < 4; ++nt) {
        int n = n0 + wn * 64 + nt * 16 + l15;
        orow[n] = acc[mt][nt][r] + bias[n];
      }
    }
  }
}

// ---------------- fused attention (S^T) + LDS-sourced depthwise conv ----------------
// 1 WG = (b,h), 512 threads (8 waves). K in LDS [197][64] swizzled chunks;
// V^T in LDS [64][260] swizzled, 260-short row stride (130 words = 2 mod 32:
// PV b64 reads ~free, conv column reads 4-way).  S computed transposed via
// MFMA(A=K,B=Q): lane holds S^T[key][tok] = the PV A-fragment -> P never
// touches LDS.  Conv per wave with lane=d (sliding 3x3 window, ~60 column
// reads/tile) into per-wave LDS convw, added in the store epilogue.
// NO global traffic beyond q/k/v reads, dwc weights, and one aout write.
__global__ __launch_bounds__(512, 4) void attn_fused(const short* __restrict__ qa, const short* __restrict__ ka,
                                                     const short* __restrict__ va,
                                                     const float* __restrict__ dwcw,
                                                     const float* __restrict__ dwcb,
                                                     short* __restrict__ aout) {
  __shared__ short Klds[197 * 64];      // 25.2 KB
  __shared__ short Vt[64 * 260];        // 33.3 KB
  __shared__ short convw[8 * 16 * 66];  // 16.9 KB  (total 75.4 KB -> 2 blocks/CU)

  const int tid = threadIdx.x;
  const int lane = tid & 63;
  const int w = tid >> 6;  // 0..7
  const int l15 = lane & 15, qd = lane >> 4;
  const int bh = blockIdx.x;
  const int b = bh / 12;
  const int h = bh - b * 12;
  const short* kb = ka + (size_t)bh * (197 * 64);
  const short* vb = va + (size_t)bh * (197 * 64);
  const short* qb = qa + (size_t)bh * (197 * 64);

  // stage K: linear LDS slots, swizzle applied to the GLOBAL chunk index
  for (int s = tid; s < 197 * 8; s += 512) {
    int row = s >> 3, cst = s & 7;
    int cg = cst ^ (row & 7);
    async16(kb + row * 64 + cg * 8, Klds + s * 8);
  }
  // stage V transposed: coalesced global u16 reads, swizzled b64 LDS writes.
  for (int t = tid; t < 64 * 52; t += 512) {
    int d = t & 63, kc4 = t >> 6;  // keys kc4*4..+3 (0..207)
    s16x4 pack;
#pragma unroll
    for (int j = 0; j < 4; ++j) {
      int key = kc4 * 4 + j;
      pack[j] = (key <= 196) ? vb[key * 64 + d] : (short)0;
    }
    int kc8 = kc4 >> 1, sub = (kc4 & 1) * 4;
    *(s16x4*)(Vt + d * 260 + ((kc8 ^ (d & 7)) << 3) + sub) = pack;
  }
  // conv weights: lane = channel d
  float wreg[9];
#pragma unroll
  for (int tp = 0; tp < 9; ++tp) wreg[tp] = dwcw[(h * 64 + lane) * 9 + tp];
  const float breg = dwcb[h * 64 + lane];

  __builtin_amdgcn_s_waitcnt(0x0f70);  // vmcnt(0) for async16
  __syncthreads();

  const float scale_log2e = 0.125f * 1.44269504f;
  const f32x4 z4 = {0.f, 0.f, 0.f, 0.f};
  short* cw = convw + w * (16 * 66);

  for (int qt = w; qt < 13; qt += 8) {
    const int m0 = qt * 16;
    int mrow = m0 + l15; if (mrow > 196) mrow = 196;
    s16x8 qf0 = *(const s16x8*)(qb + mrow * 64 + qd * 8);
    s16x8 qf1 = *(const s16x8*)(qb + mrow * 64 + 32 + qd * 8);

    // S^T = K Q^T: lane (qd,l15) holds keys kt*16+qd*4+r for tok=m0+l15
    f32x4 S[13];
#pragma unroll
    for (int kt = 0; kt < 13; ++kt) {
      int krow = kt * 16 + l15; if (krow > 196) krow = 196;
      s16x8 kf0 = *(const s16x8*)(Klds + krow * 64 + ((qd ^ (krow & 7)) << 3));
      s16x8 kf1 = *(const s16x8*)(Klds + krow * 64 + (((4 + qd) ^ (krow & 7)) << 3));
      f32x4 sa = z4;
      sa = MFMA(kf0, qf0, sa);
      sa = MFMA(kf1, qf1, sa);
      S[kt] = sa;
    }
    // mask invalid keys in tile 12 (key = 192 + qd*4 + r valid iff qd*4+r <= 4)
#pragma unroll
    for (int r = 0; r < 4; ++r)
      if (qd * 4 + r > 4) S[12][r] = -3.0e38f;

    // softmax over keys for tok=l15: in-lane (52 vals) + reduce across qd
    float mx = -3.0e38f;
#pragma unroll
    for (int kt = 0; kt < 13; ++kt)
#pragma unroll
      for (int r = 0; r < 4; ++r) mx = fmaxf(mx, S[kt][r]);
    mx = fmaxf(mx, __shfl_xor(mx, 16));
    mx = fmaxf(mx, __shfl_xor(mx, 32));

    float l = 0.f;
#pragma unroll
    for (int kt = 0; kt < 13; ++kt) {
#pragma unroll
      for (int r = 0; r < 4; ++r) {
        float p = __builtin_amdgcn_exp2f((S[kt][r] - mx) * scale_log2e);
        S[kt][r] = p;
        l += p;
      }
    }
    l += __shfl_xor(l, 16);
    l += __shfl_xor(l, 32);
    float linv = __builtin_amdgcn_rcpf(l);

    // ---- depthwise conv for this tile's tokens (lane = d, uniform tok loop) ----
    {
      const int d = lane;
      const int base = d * 260;
      const int sw = (d & 7) << 3;  // chunk-XOR term
      float vv[9];
      int py = -9, px = -9;
      for (int tl = 0; tl < 16; ++tl) {
        int tok = m0 + tl;
        if (tok > 196) break;
        if (tok == 0) { cw[d] = 0; py = -9; px = -9; continue; }
        int p = tok - 1;
        int y = p / 14, x = p - y * 14;
        if (y == py && x == px + 1) {
          vv[0] = vv[1]; vv[1] = vv[2];
          vv[3] = vv[4]; vv[4] = vv[5];
          vv[6] = vv[7]; vv[7] = vv[8];
#pragma unroll
          for (int dy = 0; dy < 3; ++dy) {
            int yy = y - 1 + dy, xx = x + 1;
            float val = 0.f;
            if (yy >= 0 && yy < 14 && xx < 14) {
              int key = 1 + yy * 14 + xx;
              val = bf2f(Vt[base + (((key >> 3) << 3) ^ sw) + (key & 7)]);
            }
            vv[dy * 3 + 2] = val;
          }
        } else {
#pragma unroll
          for (int dy = 0; dy < 3; ++dy)
#pragma unroll
            for (int dx = 0; dx < 3; ++dx) {
              int yy = y - 1 + dy, xx = x - 1 + dx;
              float val = 0.f;
              if (yy >= 0 && yy < 14 && xx >= 0 && xx < 14) {
                int key = 1 + yy * 14 + xx;
                val = bf2f(Vt[base + (((key >> 3) << 3) ^ sw) + (key & 7)]);
              }
              vv[dy * 3 + dx] = val;
            }
        }
        py = y; px = x;
        float acc = breg;
#pragma unroll
        for (int tp = 0; tp < 9; ++tp) acc += wreg[tp] * vv[tp];
        cw[tl * 66 + d] = f2bf(acc);
      }
    }

    // O = P V via 16x16x16 MFMA: A-frag (P) is the lane's OWN S values
    f32x4 O[4] = {z4, z4, z4, z4};
#pragma unroll
    for (int kt = 0; kt < 13; ++kt) {
      s16x4 a4;
#pragma unroll
      for (int r = 0; r < 4; ++r) a4[r] = f2bf(S[kt][r] * linv);
      int kc8b = kt * 2 + (qd >> 1);
      int sub = (qd & 1) * 4;
#pragma unroll
      for (int nt = 0; nt < 4; ++nt) {
        int d = nt * 16 + l15;
        s16x4 vf = *(const s16x4*)(Vt + d * 260 + ((kc8b ^ (d & 7)) << 3) + sub);
        O[nt] = MFMA16(a4, vf, O[nt]);
      }
    }

    // store epilogue: O + conv, C-layout (tok = m0+qd*4+r, d = nt*16+l15)
#pragma unroll
    for (int r = 0; r < 4; ++r) {
      int tok = m0 + qd * 4 + r;
      if (tok > 196) continue;
      size_t ob = ((size_t)b * 197 + tok) * 768 + h * 64;
      int tl = qd * 4 + r;
#pragma unroll
      for (int nt = 0; nt < 4; ++nt) {
        float cvv = bf2f(cw[tl * 66 + nt * 16 + l15]);
        aout[ob + nt * 16 + l15] = f2bf(O[nt][r] + cvv);
      }
    }
  }
}

// ---------------- launch ----------------

extern "C" void kernel_launch(void* const* d_in, const int* in_sizes, int n_in,
                              void* d_out, int out_size, void* d_ws, size_t ws_size,
                              hipStream_t stream) {
  const float* x     = (const float*)d_in[0];
  const float* Wqkv  = (const float*)d_in[1];
  const float* bqkv  = (const float*)d_in[2];
  const float* Wproj = (const float*)d_in[3];
  const float* bproj = (const float*)d_in[4];
  const float* dwcw  = (const float*)d_in[5];
  const float* dwcb  = (const float*)d_in[6];
  float* out = (float*)d_out;

  const size_t XE = (size_t)50432 * 768;
  short* ws     = (short*)d_ws;
  short* xbf    = ws;
  short* wqkvT  = xbf + XE;
  short* wprojT = wqkvT + (size_t)2304 * 768;
  short* qarr   = wprojT + (size_t)768 * 768;
  short* karr   = qarr + XE;
  short* varr   = karr + XE;
  short* aoutb  = xbf;  // reuse x_bf space (dead after gemm_qkv)

  f32_to_bf16_k<<<(int)((XE / 4 + 255) / 256), 256, 0, stream>>>(x, xbf, (int)(XE / 4));
  transpose_bf16_k<<<(2304 * 768 + 255) / 256, 256, 0, stream>>>(Wqkv, wqkvT, 768, 2304);
  transpose_bf16_k<<<(768 * 768 + 255) / 256, 256, 0, stream>>>(Wproj, wprojT, 768, 768);
  gemm_qkv<<<dim3(18, 394), 256, 0, stream>>>(xbf, wqkvT, bqkv, qarr, karr, varr);
  attn_fused<<<3072, 512, 0, stream>>>(qarr, karr, varr, dwcw, dwcb, aoutb);
  gemm_proj<<<dim3(6, 394), 256, 0, stream>>>(aoutb, wprojT, bproj, out);
}